// Round 3
// baseline (84.171 us; speedup 1.0000x reference)
//
#include <hip/hip_runtime.h>

// HybridQAE: 4-qubit encoder (RY data, CNOT chain, trainable RY; RZ phases
// cancel under |psi|^2) + MLP 4->16->32->16.
// 4 samples per thread: weight float4s (broadcast ds_read_b128) are amortized
// across 4 samples; layers 2+3 fused streaming over j2 with W3 transposed.

#define SPT 4

__global__ __launch_bounds__(256) void hqae_kernel(
    const float* __restrict__ x,
    const float* __restrict__ qw,
    const float* __restrict__ W1, const float* __restrict__ b1,
    const float* __restrict__ W2, const float* __restrict__ b2,
    const float* __restrict__ W3, const float* __restrict__ b3,
    float* __restrict__ out)
{
    __shared__ float sW1[64];      // (16,4) row-major
    __shared__ float sb1[16];
    __shared__ float sW2[512];     // (32,16) row-major
    __shared__ float sb2[32];
    __shared__ float sW3T[512];    // transposed: [j2][o], j2<32, o<16
    __shared__ float sb3[16];
    __shared__ float scw[4], ssw[4];

    const int tid = threadIdx.x;
    for (int t = tid; t < 512; t += 256) {
        sW2[t]  = W2[t];
        sW3T[t] = W3[(t & 15) * 32 + (t >> 4)];   // W3 is (16,32) row-major
    }
    if (tid < 64) sW1[tid] = W1[tid];
    if (tid < 16) { sb1[tid] = b1[tid]; sb3[tid] = b3[tid]; }
    if (tid < 32) sb2[tid] = b2[tid];
    if (tid < 4) {
        float a = qw[2 * tid] * 0.5f;   // RY half-angle; RZ weights cancel
        scw[tid] = cosf(a);
        ssw[tid] = sinf(a);
    }
    __syncthreads();

    const float cw0 = scw[0], sw0 = ssw[0];
    const float cw1 = scw[1], sw1 = ssw[1];
    const float cw2 = scw[2], sw2 = ssw[2];
    const float cw3 = scw[3], sw3 = ssw[3];

    const size_t base = ((size_t)blockIdx.x * 256 + tid) * SPT;

    float h1[SPT][16];

    // ---------- encoder + layer1, one sample at a time ----------
#pragma unroll
    for (int s = 0; s < SPT; ++s) {
        const float4* xin = reinterpret_cast<const float4*>(x + (base + s) * 16);
        float4 a0 = xin[0], a1 = xin[1], a2 = xin[2], a3 = xin[3];

        const float QPI = 0.39269908169872415f;   // pi/8: half-angle of mean*pi
        float m0 = (a0.x + a0.y + a0.z + a0.w) * QPI;
        float m1 = (a1.x + a1.y + a1.z + a1.w) * QPI;
        float m2 = (a2.x + a2.y + a2.z + a2.w) * QPI;
        float m3 = (a3.x + a3.y + a3.z + a3.w) * QPI;

        float c0 = __cosf(m0), s0 = __sinf(m0);
        float c1 = __cosf(m1), s1 = __sinf(m1);
        float c2 = __cosf(m2), s2 = __sinf(m2);
        float c3 = __cosf(m3), s3 = __sinf(m3);

        // real product state; qubit q <-> bit (3-q) of flat index
        float p[16];
        {
            float q01[4] = { c0 * c1, c0 * s1, s0 * c1, s0 * s1 };
            float q23[4] = { c2 * c3, c2 * s3, s2 * c3, s2 * s3 };
#pragma unroll
            for (int a = 0; a < 4; ++a)
#pragma unroll
                for (int b = 0; b < 4; ++b)
                    p[a * 4 + b] = q01[a] * q23[b];
        }

        // CNOT chain: compile-time permutations
#define SWAPP(A, B) { float _t = p[A]; p[A] = p[B]; p[B] = _t; }
        SWAPP(8, 12) SWAPP(9, 13) SWAPP(10, 14) SWAPP(11, 15)   // CNOT(0,1)
        SWAPP(4, 6)  SWAPP(5, 7)  SWAPP(12, 14) SWAPP(13, 15)   // CNOT(1,2)
        SWAPP(2, 3)  SWAPP(6, 7)  SWAPP(10, 11) SWAPP(14, 15)   // CNOT(2,3)
#undef SWAPP

        // trainable RY rotations (real)
#pragma unroll
        for (int k = 0; k < 8; ++k) {               // qubit0: (k, k+8)
            float u = p[k], v = p[k + 8];
            p[k] = cw0 * u - sw0 * v;  p[k + 8] = sw0 * u + cw0 * v;
        }
#pragma unroll
        for (int g = 0; g < 2; ++g)
#pragma unroll
            for (int k = 0; k < 4; ++k) {           // qubit1: (i0, i0+4)
                int i0 = g * 8 + k;
                float u = p[i0], v = p[i0 + 4];
                p[i0] = cw1 * u - sw1 * v;  p[i0 + 4] = sw1 * u + cw1 * v;
            }
#pragma unroll
        for (int g = 0; g < 4; ++g)
#pragma unroll
            for (int k = 0; k < 2; ++k) {           // qubit2: (i0, i0+2)
                int i0 = g * 4 + k;
                float u = p[i0], v = p[i0 + 2];
                p[i0] = cw2 * u - sw2 * v;  p[i0 + 2] = sw2 * u + cw2 * v;
            }
#pragma unroll
        for (int g = 0; g < 8; ++g) {               // qubit3: (i0, i0+1)
            int i0 = g * 2;
            float u = p[i0], v = p[i0 + 1];
            p[i0] = cw3 * u - sw3 * v;  p[i0 + 1] = sw3 * u + cw3 * v;
        }

        // PauliZ expvals
        float z0 = 0.f, z1 = 0.f, z2 = 0.f, z3 = 0.f;
#pragma unroll
        for (int ii = 0; ii < 16; ++ii) {
            float pr = p[ii] * p[ii];
            z0 += (ii & 8) ? -pr : pr;
            z1 += (ii & 4) ? -pr : pr;
            z2 += (ii & 2) ? -pr : pr;
            z3 += (ii & 1) ? -pr : pr;
        }

        // layer1: 4 -> 16
        const float4* w1v = reinterpret_cast<const float4*>(sW1);
#pragma unroll
        for (int j = 0; j < 16; ++j) {
            float4 w = w1v[j];
            float acc = sb1[j] + z0 * w.x + z1 * w.y + z2 * w.z + z3 * w.w;
            h1[s][j] = fmaxf(acc, 0.f);
        }
    }

    // ---------- layers 2+3 fused, streaming over j2 ----------
    float o[SPT][16];
#pragma unroll
    for (int s = 0; s < SPT; ++s)
#pragma unroll
        for (int j = 0; j < 16; ++j) o[s][j] = sb3[j];

    const float4* w2v = reinterpret_cast<const float4*>(sW2);
    const float4* w3v = reinterpret_cast<const float4*>(sW3T);

#pragma unroll
    for (int j2 = 0; j2 < 32; ++j2) {
        float4 wa = w2v[j2 * 4 + 0], wb = w2v[j2 * 4 + 1];
        float4 wc = w2v[j2 * 4 + 2], wd = w2v[j2 * 4 + 3];
        float bj = sb2[j2];
        float h2s[SPT];
#pragma unroll
        for (int s = 0; s < SPT; ++s) {
            float acc = bj;
            acc += h1[s][0]  * wa.x + h1[s][1]  * wa.y + h1[s][2]  * wa.z + h1[s][3]  * wa.w;
            acc += h1[s][4]  * wb.x + h1[s][5]  * wb.y + h1[s][6]  * wb.z + h1[s][7]  * wb.w;
            acc += h1[s][8]  * wc.x + h1[s][9]  * wc.y + h1[s][10] * wc.z + h1[s][11] * wc.w;
            acc += h1[s][12] * wd.x + h1[s][13] * wd.y + h1[s][14] * wd.z + h1[s][15] * wd.w;
            h2s[s] = fmaxf(acc, 0.f);
        }
        float4 va = w3v[j2 * 4 + 0], vb = w3v[j2 * 4 + 1];
        float4 vc = w3v[j2 * 4 + 2], vd = w3v[j2 * 4 + 3];
#pragma unroll
        for (int s = 0; s < SPT; ++s) {
            float h = h2s[s];
            o[s][0]  += h * va.x;  o[s][1]  += h * va.y;  o[s][2]  += h * va.z;  o[s][3]  += h * va.w;
            o[s][4]  += h * vb.x;  o[s][5]  += h * vb.y;  o[s][6]  += h * vb.z;  o[s][7]  += h * vb.w;
            o[s][8]  += h * vc.x;  o[s][9]  += h * vc.y;  o[s][10] += h * vc.z;  o[s][11] += h * vc.w;
            o[s][12] += h * vd.x;  o[s][13] += h * vd.y;  o[s][14] += h * vd.z;  o[s][15] += h * vd.w;
        }
    }

    // ---------- store ----------
#pragma unroll
    for (int s = 0; s < SPT; ++s) {
        float4* op = reinterpret_cast<float4*>(out + (base + s) * 16);
        op[0] = make_float4(o[s][0],  o[s][1],  o[s][2],  o[s][3]);
        op[1] = make_float4(o[s][4],  o[s][5],  o[s][6],  o[s][7]);
        op[2] = make_float4(o[s][8],  o[s][9],  o[s][10], o[s][11]);
        op[3] = make_float4(o[s][12], o[s][13], o[s][14], o[s][15]);
    }
}

extern "C" void kernel_launch(void* const* d_in, const int* in_sizes, int n_in,
                              void* d_out, int out_size, void* d_ws, size_t ws_size,
                              hipStream_t stream) {
    const float* x  = (const float*)d_in[0];
    const float* qw = (const float*)d_in[1];
    const float* W1 = (const float*)d_in[2];
    const float* b1 = (const float*)d_in[3];
    const float* W2 = (const float*)d_in[4];
    const float* b2 = (const float*)d_in[5];
    const float* W3 = (const float*)d_in[6];
    const float* b3 = (const float*)d_in[7];
    float* out = (float*)d_out;

    const int B = in_sizes[0] / 16;           // 1048576
    const int block = 256;
    hqae_kernel<<<B / (block * SPT), block, 0, stream>>>(x, qw, W1, b1, W2, b2, W3, b3, out);
}

// Round 4
// 28.277 us; speedup vs baseline: 2.9767x; 2.9767x over previous
//
#include <hip/hip_runtime.h>

// HybridQAE, fully restructured:
//  Encoder: analytic. Heisenberg-conjugating Z_q through the trainable RYs
//  (RZ drops: commutes with Z) and the CNOT chain reduces each expval to
//  products of cos/sin of the per-qubit data angles:
//    z0 = cw0*C0       - sw0*S0*S1
//    z1 = cw1*C0C1     - sw1*S1*S2
//    z2 = cw2*C0C1C2   - sw2*S2*S3
//    z3 = cw3*C0C1C2C3 - sw3*S3
//  (Cq=cos(aq), Sq=sin(aq), aq = mean(x[4q:4q+4])*pi; cwq=cos(qw[2q]).)
//  MLP: MFMA 16x16x32_f16, fp32 accum. Wave = 64 samples. M=out-features,
//  N=16-sample tiles, K padded with zero B-frags. Inter-layer transpose via
//  per-wave LDS [sample][feature] f16. Layer 3 swaps operands (D = H2^T W3^T
//  = O^T) so output is sample-major -> direct dense global stores.

typedef _Float16 f16x8 __attribute__((ext_vector_type(8)));
typedef _Float16 f16x4 __attribute__((ext_vector_type(4)));
typedef float    f32x4 __attribute__((ext_vector_type(4)));

__global__ __launch_bounds__(256) void hqae_kernel(
    const float* __restrict__ x,
    const float* __restrict__ qw,
    const float* __restrict__ W1, const float* __restrict__ b1,
    const float* __restrict__ W2, const float* __restrict__ b2,
    const float* __restrict__ W3, const float* __restrict__ b3,
    float* __restrict__ out)
{
    // ---- weights (block-shared), f16 ----
    __shared__ alignas(16) f16x8 sW1h[16];      // [m][k0..7], k>=4 zero-padded
    __shared__ alignas(16) f16x8 sW2h[64];      // (32,16): frag = [row*2 + gh]
    __shared__ alignas(16) f16x8 sW3h[64];      // (16,32): frag = [row*4 + g]
    __shared__ alignas(16) float sb1[16];
    __shared__ alignas(16) float sb2[32];
    __shared__ alignas(16) float sb3[16];
    __shared__ float scw[4], ssw[4];
    // ---- per-wave scratch (wave-private slices; no block sync needed) ----
    __shared__ alignas(16) f16x4 zbuf[4][64];    // [wv][sample] -> 4 f16
    __shared__ alignas(16) f16x4 sH1[4][256];    // [wv][sample*4 + g]
    __shared__ alignas(16) f16x4 sH2[4][512];    // [wv][sample*8 + mt*4 + g]

    const int tid = threadIdx.x;

    _Float16* w1p = (_Float16*)sW1h;
    _Float16* w2p = (_Float16*)sW2h;
    _Float16* w3p = (_Float16*)sW3h;
    for (int t = tid; t < 512; t += 256) {
        w2p[t] = (_Float16)W2[t];
        w3p[t] = (_Float16)W3[t];
    }
    if (tid < 128) w1p[tid] = ((tid & 7) < 4) ? (_Float16)W1[(tid >> 3) * 4 + (tid & 7)]
                                              : (_Float16)0.f;
    if (tid < 16) { sb1[tid] = b1[tid]; sb3[tid] = b3[tid]; }
    if (tid < 32) sb2[tid] = b2[tid];
    if (tid < 4)  { float a = qw[2 * tid]; scw[tid] = __cosf(a); ssw[tid] = __sinf(a); }
    __syncthreads();

    const int wv   = tid >> 6;
    const int lane = tid & 63;
    const int g    = lane >> 4;      // 16-lane group = K-block of MFMA frags
    const int ln15 = lane & 15;
    const int wbase = blockIdx.x * 256 + wv * 64;

    // ---------------- encoder (analytic), lane = sample ----------------
    {
        const float4* xin = reinterpret_cast<const float4*>(x + (size_t)(wbase + lane) * 16);
        float4 a0 = xin[0], a1 = xin[1], a2 = xin[2], a3 = xin[3];
        const float PI4 = 0.78539816339744831f;   // angle = mean*pi = sum*pi/4
        float t0 = (a0.x + a0.y + a0.z + a0.w) * PI4;
        float t1 = (a1.x + a1.y + a1.z + a1.w) * PI4;
        float t2 = (a2.x + a2.y + a2.z + a2.w) * PI4;
        float t3 = (a3.x + a3.y + a3.z + a3.w) * PI4;
        float C0 = __cosf(t0), S0 = __sinf(t0);
        float C1 = __cosf(t1), S1 = __sinf(t1);
        float C2 = __cosf(t2), S2 = __sinf(t2);
        float C3 = __cosf(t3), S3 = __sinf(t3);
        float C01 = C0 * C1, C012 = C01 * C2, C0123 = C012 * C3;
        float z0 = scw[0] * C0    - ssw[0] * (S0 * S1);
        float z1 = scw[1] * C01   - ssw[1] * (S1 * S2);
        float z2 = scw[2] * C012  - ssw[2] * (S2 * S3);
        float z3 = scw[3] * C0123 - ssw[3] * S3;
        f16x4 zv = { (_Float16)z0, (_Float16)z1, (_Float16)z2, (_Float16)z3 };
        zbuf[wv][lane] = zv;
    }

    // ---------------- layer 1: H1(16f x 64s) = W1(16x4) . Z ----------------
    // A = W1: lane holds A[m=ln15][k=g*8+j]; rows padded to K=8 (zeros), and
    // g>=1 lanes' A garbage is nullified by zero B there.
    f16x8 aW1 = sW1h[ln15];
    f32x4 bias1 = ((const f32x4*)sb1)[g];        // D rows m = g*4+r
#pragma unroll
    for (int st = 0; st < 4; ++st) {
        f16x4 zv = zbuf[wv][st * 16 + ln15];     // B col n = sample
        f16x8 bf = (f16x8)0;                     // k>=4 must be zero
        if (g == 0) { bf[0] = zv[0]; bf[1] = zv[1]; bf[2] = zv[2]; bf[3] = zv[3]; }
        f32x4 d = __builtin_amdgcn_mfma_f32_16x16x32_f16(aW1, bf, bias1, 0, 0, 0);
        f16x4 hv;
#pragma unroll
        for (int r = 0; r < 4; ++r) hv[r] = (_Float16)fmaxf(d[r], 0.f);
        sH1[wv][(st * 16 + ln15) * 4 + g] = hv;  // [sample][feature g*4+r]
    }

    // ---------------- layer 2: H2(32f x 64s) = W2(32x16) . H1 ----------------
    const int gh = g & 1;                        // K=16: only k-blocks 0,1 valid
    f16x8 aW2_0 = sW2h[(0 * 16 + ln15) * 2 + gh];
    f16x8 aW2_1 = sW2h[(1 * 16 + ln15) * 2 + gh];
    f32x4 bias2_0 = ((const f32x4*)sb2)[0 * 4 + g];
    f32x4 bias2_1 = ((const f32x4*)sb2)[1 * 4 + g];
#pragma unroll
    for (int st = 0; st < 4; ++st) {
        f16x8 bh = *((const f16x8*)&sH1[wv][(st * 16 + ln15) * 4] + gh);
        if (g >= 2) bh = (f16x8)0;               // k>=16 -> zero
        f32x4 d0 = __builtin_amdgcn_mfma_f32_16x16x32_f16(aW2_0, bh, bias2_0, 0, 0, 0);
        f32x4 d1 = __builtin_amdgcn_mfma_f32_16x16x32_f16(aW2_1, bh, bias2_1, 0, 0, 0);
        f16x4 hv0, hv1;
#pragma unroll
        for (int r = 0; r < 4; ++r) {
            hv0[r] = (_Float16)fmaxf(d0[r], 0.f);
            hv1[r] = (_Float16)fmaxf(d1[r], 0.f);
        }
        sH2[wv][(st * 16 + ln15) * 8 + 0 * 4 + g] = hv0;   // features g*4+r
        sH2[wv][(st * 16 + ln15) * 8 + 1 * 4 + g] = hv1;   // features 16+g*4+r
    }

    // ---------------- layer 3 (swapped): O^T = H2^T(64s x 32) . W3^T ----------------
    // "A" = H2^T: lane m=ln15 (sample-in-tile), k=g*8+j (full K=32).
    // "B" = W3^T: lane n=ln15 (out-feature), k=g*8+j -> read W3 row n.
    // D[sample][feature]: rows = samples g*4+r, col = feature ln15.
    f16x8 bW3 = sW3h[ln15 * 4 + g];
    float b3v = sb3[ln15];
    f32x4 bias3 = { b3v, b3v, b3v, b3v };
#pragma unroll
    for (int st = 0; st < 4; ++st) {
        f16x8 ah = *((const f16x8*)&sH2[wv][(st * 16 + ln15) * 8] + g);
        f32x4 d = __builtin_amdgcn_mfma_f32_16x16x32_f16(ah, bW3, bias3, 0, 0, 0);
        const size_t srow = (size_t)(wbase + st * 16 + g * 4);
#pragma unroll
        for (int r = 0; r < 4; ++r)
            out[(srow + r) * 16 + ln15] = d[r];
    }
}

extern "C" void kernel_launch(void* const* d_in, const int* in_sizes, int n_in,
                              void* d_out, int out_size, void* d_ws, size_t ws_size,
                              hipStream_t stream) {
    const float* x  = (const float*)d_in[0];
    const float* qw = (const float*)d_in[1];
    const float* W1 = (const float*)d_in[2];
    const float* b1 = (const float*)d_in[3];
    const float* W2 = (const float*)d_in[4];
    const float* b2 = (const float*)d_in[5];
    const float* W3 = (const float*)d_in[6];
    const float* b3 = (const float*)d_in[7];
    float* out = (float*)d_out;

    const int B = in_sizes[0] / 16;              // 1048576
    hqae_kernel<<<B / 256, 256, 0, stream>>>(x, qw, W1, b1, W2, b2, W3, b3, out);
}